// Round 19
// baseline (3501.715 us; speedup 1.0000x reference)
//
#include <hip/hip_runtime.h>

typedef _Float16 f16;
typedef _Float16 f16x4 __attribute__((ext_vector_type(4)));
typedef _Float16 f16x8 __attribute__((ext_vector_type(8)));
typedef float f32x4 __attribute__((ext_vector_type(4)));
typedef int i32x4 __attribute__((ext_vector_type(4)));

#define NSTEPS 512
#define NBATCH 256
#define HID 256
#define NL 3
#define NBG 8              // batch groups of 32 rows
#define NNW 4              // N-split: 64 hidden units per WG (halves redundant gather)
#define ROWS 32
#define DRING 8            // ring depth (steps)
#define PITCH 260          // f16 row pitch (520B -> 4-way A-read aliasing)
#define THREADS 256
#define FLAGSTRIDE 16      // ints per progress word (64B padding)
#define NEG_INF_I (-2000000000)

#define WPACK_OFF ((size_t)65536)               // progress flags in [0, 16KB)
#define WPACK_ELEMS ((size_t)64*16*64*8)        // f16 per layer
#define WPACK_SZB (WPACK_ELEMS*2)               // 1 MiB per layer
#define RING_OFF (WPACK_OFF + 3*WPACK_SZB)
// granule = {f16x4 payload(4 rows x 1 unit), tag, pad} = 16B; 2048/slot
#define SLOT_Q 2048
#define RING_SZB ((size_t)NL*NBG*DRING*SLOT_Q*16)
#define WS_NEEDED (RING_OFF + RING_SZB)

union Gran { i32x4 v; struct { f16x4 h; int tag; int pad; } s; };

__device__ __forceinline__ float sigm(float x){ return 1.f/(1.f+__expf(-x)); }
__device__ __forceinline__ float tanh_f(float x){ return 1.f - 2.f/(1.f+__expf(2.f*x)); }

// packed weights: [layer][nt(64)][kb(16)][lane(64)][e(8)] f16
// B-frag (mfma_f32_16x16x32_f16): col n = nt*16+(lane&15), k = kb*32+(lane>>4)*8+e.
__global__ __launch_bounds__(256) void pack_weights(
    const float* __restrict__ wih0, const float* __restrict__ whh0,
    const float* __restrict__ wih1, const float* __restrict__ whh1,
    const float* __restrict__ wih2, const float* __restrict__ whh2,
    unsigned char* __restrict__ ws)
{
  int gid = blockIdx.x*256 + threadIdx.x;
  if (gid >= 3*64*16*64) return;
  int lane  = gid & 63;
  int kb    = (gid>>6) & 15;
  int nt    = (gid>>10) & 63;
  int layer = gid>>16;
  const float* whh = (layer==0)?whh0:((layer==1)?whh1:whh2);
  const float* wih = (layer==0)?wih0:((layer==1)?wih1:wih2);
  int indim = (layer==0)?12:256;
  int n  = nt*16 + (lane&15);
  int k0 = kb*32 + (lane>>4)*8;
  f16x8 v;
  #pragma unroll
  for (int e=0;e<8;++e){
    int k = k0+e;
    float x;
    if (k < HID) x = whh[n*HID + k];
    else { int ki = k-HID; x = (ki<indim)? wih[n*indim+ki] : 0.f; }
    v[e] = (f16)x;
  }
  f16* dst = (f16*)(ws + WPACK_OFF) + (size_t)layer*WPACK_ELEMS
           + ((size_t)(nt*16+kb)*64 + lane)*8;
  *(f16x8*)dst = v;
}

// 96 WGs = 3 layers x 8 batch-groups x 4 N-groups (64 units each).
// Weights VGPR-stationary (256 VGPRs/wave; 1 wave/SIMD). Each wave computes
// its 16-unit column for all 4 gates over BOTH 16-row tiles (8 MFMA/kb).
// Cross-WG h: 16B self-validating granules (tag in-band, sc0 sc1); consumers
// poll the DATA (proven full-reload retry). Structure otherwise == R14.
__global__ __launch_bounds__(THREADS, 1) void lstm_ws(
    const float* __restrict__ input,
    const float* __restrict__ bih0, const float* __restrict__ bhh0,
    const float* __restrict__ bih1, const float* __restrict__ bhh1,
    const float* __restrict__ bih2, const float* __restrict__ bhh2,
    const float* __restrict__ wlin, const float* __restrict__ blin,
    unsigned char* __restrict__ ws, float* __restrict__ out)
{
  __shared__ __attribute__((aligned(16))) f16 Hown[ROWS*PITCH];  // 16640 B
  __shared__ __attribute__((aligned(16))) f16 Hin [ROWS*PITCH];  // 16640 B
  __shared__ float wlinLDS[HID];

  const int tid  = threadIdx.x;
  const int w    = tid >> 6;          // 4 waves = 4 unit16 columns
  const int lane = tid & 63;
  const int c16  = lane & 15;
  const int bid  = blockIdx.x;
  const int bg   = bid & 7;
  const int nq   = (bid >> 3) & 3;
  const int layer= bid >> 5;
  const int rowsBase = bg * ROWS;
  const int unitBase = nq * 64;

  int* flags = (int*)ws;
  int* progSelf = flags + (layer*NBG + bg)*8*FLAGSTRIDE;
  int* progUp   = (layer<2)? flags + ((layer+1)*NBG + bg)*8*FLAGSTRIDE : progSelf;

  const f16x8* wpv = (const f16x8*)((const f16*)(ws + WPACK_OFF) + (size_t)layer*WPACK_ELEMS);
  i32x4* ringSelf = (i32x4*)(ws + RING_OFF) + (size_t)((layer*NBG + bg)*DRING)*SLOT_Q;
  i32x4* ringLow  = (layer>0)? (i32x4*)(ws + RING_OFF) + (size_t)(((layer-1)*NBG + bg)*DRING)*SLOT_Q : (i32x4*)0;

  // ---- one-time: this wave's 64 B-fragments -> VGPRs (256 VGPRs) ----
  f16x8 bfr[4][16];
  #pragma unroll
  for (int G=0; G<4; ++G){
    const int nt = G*16 + nq*4 + w;
    #pragma unroll
    for (int kb=0; kb<16; ++kb)
      bfr[G][kb] = wpv[(size_t)nt*1024 + kb*64 + lane];
  }
  if (tid < HID) wlinLDS[tid] = wlin[tid];

  const float* BIH = (layer==0)?bih0:((layer==1)?bih1:bih2);
  const float* BHH = (layer==0)?bhh0:((layer==1)?bhh1:bhh2);
  float bias[4], cst0[4], cst1[4];
  const int unit = unitBase + w*16 + c16;
  #pragma unroll
  for (int G=0;G<4;++G){
    int n = G*HID + unit;
    bias[G] = BIH[n] + BHH[n];
    cst0[G] = 0.f; cst1[G] = 0.f;                   // reused as [q], per m-tile
  }
  const float bl = blin[0];
  const int rb0 = lane>>4;                          // m=0 rowblk (rows 0-15)
  const int rb1 = 4 + (lane>>4);                    // m=1 rowblk (rows 16-31)
  const int kbv = (layer==0)? 9 : 16;

  for (int i=tid; i<ROWS*PITCH; i+=THREADS){ Hown[i]=(f16)0.f; Hin[i]=(f16)0.f; }
  __syncthreads();

  for (int t=0; t<NSTEPS; ++t){
    // ---- amortized backpressure: every 4th step, upper progress >= t-4 ----
    if (layer<2 && (t&3)==0 && t>4){
      bool act = lane < 4;
      const int* p = progUp + (lane&3)*FLAGSTRIDE;
      int need = act ? t-4 : NEG_INF_I;
      int guard = 0;
      for(;;){
        int v = act ? __hip_atomic_load(p, __ATOMIC_RELAXED, __HIP_MEMORY_SCOPE_AGENT) : 0;
        if (__all(v >= need)) break;
        if (++guard > (1<<18)) break;               // bounded: fail visibly
        __builtin_amdgcn_s_sleep(1);
      }
    }

    // ---- layer-0 input staging (no ring) ----
    if (layer == 0){
      for (int idx=tid; idx<ROWS*12; idx+=THREADS){
        int r = idx/12, i = idx - r*12;
        Hin[r*PITCH + i] = (f16)input[((size_t)t*NBATCH + rowsBase + r)*12 + i];
      }
    }

    // ---- tag-in-band staging: poll data granules until tags current ----
    {
      Gran go[8], gl[8];
      const i32x4* srcO = ringSelf + (size_t)((t-1)&(DRING-1))*SLOT_Q + tid;
      const i32x4* srcL = (layer>0)? ringLow + (size_t)(t&(DRING-1))*SLOT_Q + tid : (i32x4*)0;
      const bool doOwn = (t>0), doLow = (layer>0);
      int guard = 0;
      for(;;){
        if (doOwn){
          #pragma unroll
          for (int it=0; it<8; ++it)
            asm volatile("global_load_dwordx4 %0, %1, off sc0 sc1"
                         : "=v"(go[it].v) : "v"(srcO + it*THREADS) : "memory");
        }
        if (doLow){
          #pragma unroll
          for (int it=0; it<8; ++it)
            asm volatile("global_load_dwordx4 %0, %1, off sc0 sc1"
                         : "=v"(gl[it].v) : "v"(srcL + it*THREADS) : "memory");
        }
        asm volatile("s_waitcnt vmcnt(0)" ::: "memory");
        __builtin_amdgcn_sched_barrier(0);
        bool ok = true;
        if (doOwn){
          #pragma unroll
          for (int it=0; it<8; ++it) ok = ok && (go[it].s.tag >= t-1);
        }
        if (doLow){
          #pragma unroll
          for (int it=0; it<8; ++it) ok = ok && (gl[it].s.tag >= t);
        }
        if (ok || ++guard > (1<<18)) break;          // guard: fail visibly
      }
      if (doOwn){
        #pragma unroll
        for (int it=0; it<8; ++it){
          int i = tid + it*THREADS, rb = i>>8, un = i&255;
          f16* base = &Hown[(rb*4)*PITCH + un];
          base[0]=go[it].s.h[0]; base[PITCH]=go[it].s.h[1];
          base[2*PITCH]=go[it].s.h[2]; base[3*PITCH]=go[it].s.h[3];
        }
      }
      if (doLow){
        #pragma unroll
        for (int it=0; it<8; ++it){
          int i = tid + it*THREADS, rb = i>>8, un = i&255;
          f16* base = &Hin[(rb*4)*PITCH + un];
          base[0]=gl[it].s.h[0]; base[PITCH]=gl[it].s.h[1];
          base[2*PITCH]=gl[it].s.h[2]; base[3*PITCH]=gl[it].s.h[3];
        }
      }
    }
    __syncthreads();                                  // #1: stage -> GEMM

    // ---- progress publish (backpressure producer, off critical path) ----
    if (layer>0 && (t&3)==3 && tid==0)
      __hip_atomic_store(progSelf + nq*FLAGSTRIDE, t+1,
                         __ATOMIC_RELAXED, __HIP_MEMORY_SCOPE_AGENT);

    // ---- gates GEMM (B from VGPRs, A from LDS, both 16-row tiles) + cell ----
    f32x4 a00={bias[0],bias[0],bias[0],bias[0]}; f32x4 a01=a00;
    f32x4 a10={bias[1],bias[1],bias[1],bias[1]}; f32x4 a11=a10;
    f32x4 a20={bias[2],bias[2],bias[2],bias[2]}; f32x4 a21=a20;
    f32x4 a30={bias[3],bias[3],bias[3],bias[3]}; f32x4 a31=a30;
    #pragma unroll
    for (int kb=0; kb<16; ++kb){
      if (kb < kbv){
        const f16* base = (kb<8) ? Hown : Hin;
        const int kk = (kb&7)*32 + (lane>>4)*8;
        f16x8 am0 = *(const f16x8*)&base[c16*PITCH + kk];
        f16x8 am1 = *(const f16x8*)&base[(16+c16)*PITCH + kk];
        a00 = __builtin_amdgcn_mfma_f32_16x16x32_f16(am0, bfr[0][kb], a00, 0,0,0);
        a01 = __builtin_amdgcn_mfma_f32_16x16x32_f16(am1, bfr[0][kb], a01, 0,0,0);
        a10 = __builtin_amdgcn_mfma_f32_16x16x32_f16(am0, bfr[1][kb], a10, 0,0,0);
        a11 = __builtin_amdgcn_mfma_f32_16x16x32_f16(am1, bfr[1][kb], a11, 0,0,0);
        a20 = __builtin_amdgcn_mfma_f32_16x16x32_f16(am0, bfr[2][kb], a20, 0,0,0);
        a21 = __builtin_amdgcn_mfma_f32_16x16x32_f16(am1, bfr[2][kb], a21, 0,0,0);
        a30 = __builtin_amdgcn_mfma_f32_16x16x32_f16(am0, bfr[3][kb], a30, 0,0,0);
        a31 = __builtin_amdgcn_mfma_f32_16x16x32_f16(am1, bfr[3][kb], a31, 0,0,0);
      }
    }

    Gran gg0, gg1;
    #pragma unroll
    for (int q=0;q<4;++q){
      float gi = sigm  (a00[q]);
      float gf = sigm  (a10[q]);
      float gG = tanh_f(a20[q]);
      float go_ = sigm (a30[q]);
      float cv = gf*cst0[q] + gi*gG; cst0[q]=cv;
      gg0.s.h[q] = (f16)(go_*tanh_f(cv));
    }
    #pragma unroll
    for (int q=0;q<4;++q){
      float gi = sigm  (a01[q]);
      float gf = sigm  (a11[q]);
      float gG = tanh_f(a21[q]);
      float go_ = sigm (a31[q]);
      float cv = gf*cst1[q] + gi*gG; cst1[q]=cv;
      gg1.s.h[q] = (f16)(go_*tanh_f(cv));
    }
    gg0.s.tag = t; gg0.s.pad = 0;
    gg1.s.tag = t; gg1.s.pad = 0;
    // ---- publish: TWO self-validating 16B stores, fire-and-forget ----
    {
      i32x4* slot = ringSelf + (size_t)(t&(DRING-1))*SLOT_Q;
      i32x4* dst0 = slot + rb0*256 + unit;
      i32x4* dst1 = slot + rb1*256 + unit;
      asm volatile("global_store_dwordx4 %0, %1, off sc0 sc1"
                   :: "v"(dst0), "v"(gg0.v) : "memory");
      asm volatile("global_store_dwordx4 %0, %1, off sc0 sc1"
                   :: "v"(dst1), "v"(gg1.v) : "memory");
    }

    // ---- head (layer 2): out[t-1] from Hown (h_{t-1}) ----
    if (layer==2 && t>0){
      int row = tid>>3, kc = tid&7;
      float s = 0.f;
      #pragma unroll
      for (int cc=0; cc<4; ++cc){
        f16x8 hv = *(const f16x8*)&Hown[row*PITCH + kc*32 + cc*8];
        #pragma unroll
        for (int j=0;j<8;++j) s += (float)hv[j] * wlinLDS[kc*32 + cc*8 + j];
      }
      s += __shfl_xor(s,1); s += __shfl_xor(s,2); s += __shfl_xor(s,4);
      if (kc==0) out[(size_t)(t-1)*NBATCH + rowsBase + row] = s + bl;
    }
    __syncthreads();                                  // #2: reads done -> next stage
  }

  // ---- epilogue: out[511] from h_511 (layer 2) ----
  if (layer==2){
    Gran go[8];
    const i32x4* srcO = ringSelf + (size_t)((NSTEPS-1)&(DRING-1))*SLOT_Q + tid;
    int guard = 0;
    for(;;){
      #pragma unroll
      for (int it=0; it<8; ++it)
        asm volatile("global_load_dwordx4 %0, %1, off sc0 sc1"
                     : "=v"(go[it].v) : "v"(srcO + it*THREADS) : "memory");
      asm volatile("s_waitcnt vmcnt(0)" ::: "memory");
      __builtin_amdgcn_sched_barrier(0);
      bool ok = true;
      #pragma unroll
      for (int it=0; it<8; ++it) ok = ok && (go[it].s.tag >= NSTEPS-1);
      if (ok || ++guard > (1<<18)) break;
    }
    #pragma unroll
    for (int it=0; it<8; ++it){
      int i = tid + it*THREADS, rb = i>>8, un = i&255;
      f16* base = &Hown[(rb*4)*PITCH + un];
      base[0]=go[it].s.h[0]; base[PITCH]=go[it].s.h[1];
      base[2*PITCH]=go[it].s.h[2]; base[3*PITCH]=go[it].s.h[3];
    }
    __syncthreads();
    int row = tid>>3, kc = tid&7;
    float s = 0.f;
    #pragma unroll
    for (int cc=0; cc<4; ++cc){
      f16x8 hv = *(const f16x8*)&Hown[row*PITCH + kc*32 + cc*8];
      #pragma unroll
      for (int j=0;j<8;++j) s += (float)hv[j] * wlinLDS[kc*32 + cc*8 + j];
    }
    s += __shfl_xor(s,1); s += __shfl_xor(s,2); s += __shfl_xor(s,4);
    if (kc==0) out[(size_t)(NSTEPS-1)*NBATCH + rowsBase + row] = s + bl;
  }
}

extern "C" void kernel_launch(void* const* d_in, const int* in_sizes, int n_in,
                              void* d_out, int out_size, void* d_ws, size_t ws_size,
                              hipStream_t stream)
{
  const float* input=(const float*)d_in[0];
  const float* wih0 =(const float*)d_in[1];
  const float* whh0 =(const float*)d_in[2];
  const float* bih0 =(const float*)d_in[3];
  const float* bhh0 =(const float*)d_in[4];
  const float* wih1 =(const float*)d_in[5];
  const float* whh1 =(const float*)d_in[6];
  const float* bih1 =(const float*)d_in[7];
  const float* bhh1 =(const float*)d_in[8];
  const float* wih2 =(const float*)d_in[9];
  const float* whh2 =(const float*)d_in[10];
  const float* bih2 =(const float*)d_in[11];
  const float* bhh2 =(const float*)d_in[12];
  const float* wlin =(const float*)d_in[13];
  const float* blin =(const float*)d_in[14];
  unsigned char* ws = (unsigned char*)d_ws;
  if (ws_size < WS_NEEDED) return;   // ~9.5 MB needed

  (void)hipMemsetAsync(ws, 0, WPACK_OFF, stream);                 // progress flags
  (void)hipMemsetAsync(ws + RING_OFF, 0xFF, RING_SZB, stream);    // ring tags = -1
  hipLaunchKernelGGL(pack_weights, dim3(768), dim3(256), 0, stream,
                     wih0,whh0,wih1,whh1,wih2,whh2, ws);
  hipLaunchKernelGGL(lstm_ws, dim3(NL*NBG*NNW), dim3(THREADS), 0, stream,
                     input, bih0,bhh0,bih1,bhh1,bih2,bhh2, wlin, blin,
                     ws, (float*)d_out);
}

// Round 20
// 2303.791 us; speedup vs baseline: 1.5200x; 1.5200x over previous
//
#include <hip/hip_runtime.h>

typedef _Float16 f16;
typedef _Float16 f16x4 __attribute__((ext_vector_type(4)));
typedef _Float16 f16x8 __attribute__((ext_vector_type(8)));
typedef float f32x4 __attribute__((ext_vector_type(4)));
typedef int i32x4 __attribute__((ext_vector_type(4)));

#define NSTEPS 512
#define NBATCH 256
#define HID 256
#define NL 3
#define NBG 8              // batch groups of 32 rows
#define NNW 8              // N-split: 32 hidden units per WG
#define ROWS 32
#define DRING 8            // ring depth (steps)
#define PITCH 260          // f16 row pitch (520B -> 4-way A-read aliasing)
#define THREADS 256
#define FLAGSTRIDE 16      // ints per progress word (64B padding)
#define NEG_INF_I (-2000000000)

#define WPACK_OFF ((size_t)65536)               // progress flags in [0, 16KB)
#define WPACK_ELEMS ((size_t)64*16*64*8)        // f16 per layer
#define WPACK_SZB (WPACK_ELEMS*2)               // 1 MiB per layer
#define RING_OFF (WPACK_OFF + 3*WPACK_SZB)
// granule = {f16x4 payload(4 rows x 1 unit), tag, pad} = 16B; 2048/slot
#define SLOT_Q 2048
#define RING_SZB ((size_t)NL*NBG*DRING*SLOT_Q*16)
#define WS_NEEDED (RING_OFF + RING_SZB)

union Gran { i32x4 v; struct { f16x4 h; int tag; int pad; } s; };

__device__ __forceinline__ float sigm(float x){ return 1.f/(1.f+__expf(-x)); }
__device__ __forceinline__ float tanh_f(float x){ return 1.f - 2.f/(1.f+__expf(2.f*x)); }

// packed weights: [layer][nt(64)][kb(16)][lane(64)][e(8)] f16
// B-frag (mfma_f32_16x16x32_f16): col n = nt*16+(lane&15), k = kb*32+(lane>>4)*8+e.
__global__ __launch_bounds__(256) void pack_weights(
    const float* __restrict__ wih0, const float* __restrict__ whh0,
    const float* __restrict__ wih1, const float* __restrict__ whh1,
    const float* __restrict__ wih2, const float* __restrict__ whh2,
    unsigned char* __restrict__ ws)
{
  int gid = blockIdx.x*256 + threadIdx.x;
  if (gid >= 3*64*16*64) return;
  int lane  = gid & 63;
  int kb    = (gid>>6) & 15;
  int nt    = (gid>>10) & 63;
  int layer = gid>>16;
  const float* whh = (layer==0)?whh0:((layer==1)?whh1:whh2);
  const float* wih = (layer==0)?wih0:((layer==1)?wih1:wih2);
  int indim = (layer==0)?12:256;
  int n  = nt*16 + (lane&15);
  int k0 = kb*32 + (lane>>4)*8;
  f16x8 v;
  #pragma unroll
  for (int e=0;e<8;++e){
    int k = k0+e;
    float x;
    if (k < HID) x = whh[n*HID + k];
    else { int ki = k-HID; x = (ki<indim)? wih[n*indim+ki] : 0.f; }
    v[e] = (f16)x;
  }
  f16* dst = (f16*)(ws + WPACK_OFF) + (size_t)layer*WPACK_ELEMS
           + ((size_t)(nt*16+kb)*64 + lane)*8;
  *(f16x8*)dst = v;
}

// 192 WGs = 3 layers x 8 batch-groups x 8 N-groups.
// Weights VGPR-stationary (256 VGPRs/wave of B-fragments; 1 wave/SIMD).
// Cross-WG h: 16B self-validating granules (tag in-band, sc0 sc1); consumers
// poll the DATA (full-reload retry). Best-known configuration (R14).
__global__ __launch_bounds__(THREADS, 1) void lstm_ws(
    const float* __restrict__ input,
    const float* __restrict__ bih0, const float* __restrict__ bhh0,
    const float* __restrict__ bih1, const float* __restrict__ bhh1,
    const float* __restrict__ bih2, const float* __restrict__ bhh2,
    const float* __restrict__ wlin, const float* __restrict__ blin,
    unsigned char* __restrict__ ws, float* __restrict__ out)
{
  __shared__ __attribute__((aligned(16))) f16 Hown[ROWS*PITCH];  // 16640 B
  __shared__ __attribute__((aligned(16))) f16 Hin [ROWS*PITCH];  // 16640 B
  __shared__ float wlinLDS[HID];

  const int tid  = threadIdx.x;
  const int w    = tid >> 6;          // 4 waves
  const int wm   = w >> 1, wn = w & 1;
  const int lane = tid & 63;
  const int c16  = lane & 15;
  const int r0   = (lane >> 4) * 4;
  const int bid  = blockIdx.x;
  const int bg   = bid & 7;
  const int nw   = (bid >> 3) & 7;
  const int layer= bid >> 6;
  const int rowsBase = bg * ROWS;
  const int unitBase = nw * 32;
  const int arow = wm*16 + c16;

  int* flags = (int*)ws;
  int* progSelf = flags + (layer*NBG + bg)*8*FLAGSTRIDE;
  int* progUp   = (layer<2)? flags + ((layer+1)*NBG + bg)*8*FLAGSTRIDE : progSelf;

  const f16x8* wpv = (const f16x8*)((const f16*)(ws + WPACK_OFF) + (size_t)layer*WPACK_ELEMS);
  i32x4* ringSelf = (i32x4*)(ws + RING_OFF) + (size_t)((layer*NBG + bg)*DRING)*SLOT_Q;
  i32x4* ringLow  = (layer>0)? (i32x4*)(ws + RING_OFF) + (size_t)(((layer-1)*NBG + bg)*DRING)*SLOT_Q : (i32x4*)0;

  // ---- one-time: this wave's 64 B-fragments -> VGPRs (256 VGPRs) ----
  f16x8 bfr[4][16];
  #pragma unroll
  for (int G=0; G<4; ++G){
    const int nt = G*16 + nw*2 + wn;
    #pragma unroll
    for (int kb=0; kb<16; ++kb)
      bfr[G][kb] = wpv[(size_t)nt*1024 + kb*64 + lane];
  }
  if (tid < HID) wlinLDS[tid] = wlin[tid];

  const float* BIH = (layer==0)?bih0:((layer==1)?bih1:bih2);
  const float* BHH = (layer==0)?bhh0:((layer==1)?bhh1:bhh2);
  float bias[4], cst[4];
  const int unit = unitBase + wn*16 + c16;
  #pragma unroll
  for (int G=0;G<4;++G){
    int n = G*HID + unit;
    bias[G] = BIH[n] + BHH[n];
    cst[G] = 0.f;                                   // reused as [q]
  }
  const float bl = blin[0];
  const int rowblk = wm*4 + (lane>>4);              // this lane's 4-row block
  const int kbv = (layer==0)? 9 : 16;

  for (int i=tid; i<ROWS*PITCH; i+=THREADS){ Hown[i]=(f16)0.f; Hin[i]=(f16)0.f; }
  __syncthreads();

  for (int t=0; t<NSTEPS; ++t){
    // ---- amortized backpressure: every 4th step, upper progress >= t-4 ----
    if (layer<2 && (t&3)==0 && t>4){
      bool act = lane < 8;
      const int* p = progUp + (lane&7)*FLAGSTRIDE;
      int need = act ? t-4 : NEG_INF_I;
      int guard = 0;
      for(;;){
        int v = act ? __hip_atomic_load(p, __ATOMIC_RELAXED, __HIP_MEMORY_SCOPE_AGENT) : 0;
        if (__all(v >= need)) break;
        if (++guard > (1<<18)) break;               // bounded: fail visibly
        __builtin_amdgcn_s_sleep(1);
      }
    }

    // ---- layer-0 input staging (no ring) ----
    if (layer == 0){
      for (int idx=tid; idx<ROWS*12; idx+=THREADS){
        int r = idx/12, i = idx - r*12;
        Hin[r*PITCH + i] = (f16)input[((size_t)t*NBATCH + rowsBase + r)*12 + i];
      }
    }

    // ---- tag-in-band staging: poll data granules until tags current ----
    {
      Gran go[8], gl[8];
      const i32x4* srcO = ringSelf + (size_t)((t-1)&(DRING-1))*SLOT_Q + tid;
      const i32x4* srcL = (layer>0)? ringLow + (size_t)(t&(DRING-1))*SLOT_Q + tid : (i32x4*)0;
      const bool doOwn = (t>0), doLow = (layer>0);
      int guard = 0;
      for(;;){
        if (doOwn){
          #pragma unroll
          for (int it=0; it<8; ++it)
            asm volatile("global_load_dwordx4 %0, %1, off sc0 sc1"
                         : "=v"(go[it].v) : "v"(srcO + it*THREADS) : "memory");
        }
        if (doLow){
          #pragma unroll
          for (int it=0; it<8; ++it)
            asm volatile("global_load_dwordx4 %0, %1, off sc0 sc1"
                         : "=v"(gl[it].v) : "v"(srcL + it*THREADS) : "memory");
        }
        asm volatile("s_waitcnt vmcnt(0)" ::: "memory");
        __builtin_amdgcn_sched_barrier(0);
        bool ok = true;
        if (doOwn){
          #pragma unroll
          for (int it=0; it<8; ++it) ok = ok && (go[it].s.tag >= t-1);
        }
        if (doLow){
          #pragma unroll
          for (int it=0; it<8; ++it) ok = ok && (gl[it].s.tag >= t);
        }
        if (ok || ++guard > (1<<18)) break;          // guard: fail visibly
      }
      if (doOwn){
        #pragma unroll
        for (int it=0; it<8; ++it){
          int i = tid + it*THREADS, rb = i>>8, un = i&255;
          f16* base = &Hown[(rb*4)*PITCH + un];
          base[0]=go[it].s.h[0]; base[PITCH]=go[it].s.h[1];
          base[2*PITCH]=go[it].s.h[2]; base[3*PITCH]=go[it].s.h[3];
        }
      }
      if (doLow){
        #pragma unroll
        for (int it=0; it<8; ++it){
          int i = tid + it*THREADS, rb = i>>8, un = i&255;
          f16* base = &Hin[(rb*4)*PITCH + un];
          base[0]=gl[it].s.h[0]; base[PITCH]=gl[it].s.h[1];
          base[2*PITCH]=gl[it].s.h[2]; base[3*PITCH]=gl[it].s.h[3];
        }
      }
    }
    __syncthreads();                                  // #1: stage -> GEMM

    // ---- progress publish (backpressure producer, off critical path) ----
    if (layer>0 && (t&3)==3 && tid==0)
      __hip_atomic_store(progSelf + nw*FLAGSTRIDE, t+1,
                         __ATOMIC_RELAXED, __HIP_MEMORY_SCOPE_AGENT);

    // ---- gates GEMM (B from VGPRs, A from LDS) + cell ----
    f32x4 acc0={bias[0],bias[0],bias[0],bias[0]};
    f32x4 acc1={bias[1],bias[1],bias[1],bias[1]};
    f32x4 acc2={bias[2],bias[2],bias[2],bias[2]};
    f32x4 acc3={bias[3],bias[3],bias[3],bias[3]};
    #pragma unroll
    for (int kb=0; kb<16; ++kb){
      if (kb < kbv){
        const f16* ap = (kb<8) ? &Hown[arow*PITCH + kb*32 + (lane>>4)*8]
                               : &Hin [arow*PITCH + (kb-8)*32 + (lane>>4)*8];
        f16x8 a = *(const f16x8*)ap;
        acc0 = __builtin_amdgcn_mfma_f32_16x16x32_f16(a, bfr[0][kb], acc0, 0,0,0);
        acc1 = __builtin_amdgcn_mfma_f32_16x16x32_f16(a, bfr[1][kb], acc1, 0,0,0);
        acc2 = __builtin_amdgcn_mfma_f32_16x16x32_f16(a, bfr[2][kb], acc2, 0,0,0);
        acc3 = __builtin_amdgcn_mfma_f32_16x16x32_f16(a, bfr[3][kb], acc3, 0,0,0);
      }
    }

    Gran gg;
    #pragma unroll
    for (int q=0;q<4;++q){
      float gi = sigm  (acc0[q]);
      float gf = sigm  (acc1[q]);
      float gg_ = tanh_f(acc2[q]);
      float go_ = sigm  (acc3[q]);
      float cv = gf*cst[q] + gi*gg_; cst[q]=cv;
      gg.s.h[q] = (f16)(go_*tanh_f(cv));
    }
    gg.s.tag = t; gg.s.pad = 0;
    // ---- publish: ONE self-validating 16B store, fire-and-forget ----
    {
      i32x4* dst = ringSelf + (size_t)(t&(DRING-1))*SLOT_Q + rowblk*256 + unit;
      asm volatile("global_store_dwordx4 %0, %1, off sc0 sc1"
                   :: "v"(dst), "v"(gg.v) : "memory");
    }

    // ---- head (layer 2): out[t-1] from Hown (h_{t-1}) ----
    if (layer==2 && t>0){
      int row = tid>>3, kc = tid&7;
      float s = 0.f;
      #pragma unroll
      for (int cc=0; cc<4; ++cc){
        f16x8 hv = *(const f16x8*)&Hown[row*PITCH + kc*32 + cc*8];
        #pragma unroll
        for (int j=0;j<8;++j) s += (float)hv[j] * wlinLDS[kc*32 + cc*8 + j];
      }
      s += __shfl_xor(s,1); s += __shfl_xor(s,2); s += __shfl_xor(s,4);
      if (kc==0) out[(size_t)(t-1)*NBATCH + rowsBase + row] = s + bl;
    }
    __syncthreads();                                  // #2: reads done -> next stage
  }

  // ---- epilogue: out[511] from h_511 (layer 2) ----
  if (layer==2){
    Gran go[8];
    const i32x4* srcO = ringSelf + (size_t)((NSTEPS-1)&(DRING-1))*SLOT_Q + tid;
    int guard = 0;
    for(;;){
      #pragma unroll
      for (int it=0; it<8; ++it)
        asm volatile("global_load_dwordx4 %0, %1, off sc0 sc1"
                     : "=v"(go[it].v) : "v"(srcO + it*THREADS) : "memory");
      asm volatile("s_waitcnt vmcnt(0)" ::: "memory");
      __builtin_amdgcn_sched_barrier(0);
      bool ok = true;
      #pragma unroll
      for (int it=0; it<8; ++it) ok = ok && (go[it].s.tag >= NSTEPS-1);
      if (ok || ++guard > (1<<18)) break;
    }
    #pragma unroll
    for (int it=0; it<8; ++it){
      int i = tid + it*THREADS, rb = i>>8, un = i&255;
      f16* base = &Hown[(rb*4)*PITCH + un];
      base[0]=go[it].s.h[0]; base[PITCH]=go[it].s.h[1];
      base[2*PITCH]=go[it].s.h[2]; base[3*PITCH]=go[it].s.h[3];
    }
    __syncthreads();
    int row = tid>>3, kc = tid&7;
    float s = 0.f;
    #pragma unroll
    for (int cc=0; cc<4; ++cc){
      f16x8 hv = *(const f16x8*)&Hown[row*PITCH + kc*32 + cc*8];
      #pragma unroll
      for (int j=0;j<8;++j) s += (float)hv[j] * wlinLDS[kc*32 + cc*8 + j];
    }
    s += __shfl_xor(s,1); s += __shfl_xor(s,2); s += __shfl_xor(s,4);
    if (kc==0) out[(size_t)(NSTEPS-1)*NBATCH + rowsBase + row] = s + bl;
  }
}

extern "C" void kernel_launch(void* const* d_in, const int* in_sizes, int n_in,
                              void* d_out, int out_size, void* d_ws, size_t ws_size,
                              hipStream_t stream)
{
  const float* input=(const float*)d_in[0];
  const float* wih0 =(const float*)d_in[1];
  const float* whh0 =(const float*)d_in[2];
  const float* bih0 =(const float*)d_in[3];
  const float* bhh0 =(const float*)d_in[4];
  const float* wih1 =(const float*)d_in[5];
  const float* whh1 =(const float*)d_in[6];
  const float* bih1 =(const float*)d_in[7];
  const float* bhh1 =(const float*)d_in[8];
  const float* wih2 =(const float*)d_in[9];
  const float* whh2 =(const float*)d_in[10];
  const float* bih2 =(const float*)d_in[11];
  const float* bhh2 =(const float*)d_in[12];
  const float* wlin =(const float*)d_in[13];
  const float* blin =(const float*)d_in[14];
  unsigned char* ws = (unsigned char*)d_ws;
  if (ws_size < WS_NEEDED) return;   // ~9.5 MB needed

  (void)hipMemsetAsync(ws, 0, WPACK_OFF, stream);                 // progress flags
  (void)hipMemsetAsync(ws + RING_OFF, 0xFF, RING_SZB, stream);    // ring tags = -1
  hipLaunchKernelGGL(pack_weights, dim3(768), dim3(256), 0, stream,
                     wih0,whh0,wih1,whh1,wih2,whh2, ws);
  hipLaunchKernelGGL(lstm_ws, dim3(NL*NBG*NNW), dim3(THREADS), 0, stream,
                     input, bih0,bhh0,bih1,bhh1,bih2,bhh2, wlin, blin,
                     ws, (float*)d_out);
}